// Round 1
// 1181.610 us; speedup vs baseline: 1.0803x; 1.0803x over previous
//
#include <hip/hip_runtime.h>

// Causal self-attention, B=2 S=2048 D=2048 H=16 DK=128.
// d_out = [out: 4096*2048 f32][attn: 2*16*2048*2048 f32]
// ws layout (bf16): qb,kb [B,H,S,DK], vT [B,H,DK,S], xb [B,S,D],
//                   qf,kf,vf [B,S,D] (converted inputs), wq,wk,wv,wo [D,D]
//                   = 7*NE + 4*NW elems = 151 MB

#define BATCH 2
#define S_LEN 2048
#define D_DIM 2048
#define H_NUM 16
#define DKD   128

typedef __attribute__((ext_vector_type(8))) short  short8;   // 8 bf16 = 4 VGPR
typedef __attribute__((ext_vector_type(4))) short  short4v;  // 4 bf16 = 8 B
typedef __attribute__((ext_vector_type(4))) float  floatx4;

__device__ __forceinline__ unsigned short f2bf(float f) {
    unsigned int u = __float_as_uint(f);
    u += 0x7fffu + ((u >> 16) & 1u);   // round-to-nearest-even
    return (unsigned short)(u >> 16);
}

__device__ __forceinline__ void gload16(const void* g, void* l) {
    __builtin_amdgcn_global_load_lds(
        (const __attribute__((address_space(1))) void*)g,
        (__attribute__((address_space(3))) void*)l, 16, 0, 0);
}

// bf16 source: 128(row) x 32(k) tile via global_load_lds width=16.
// LDS linear [128][32]; per (wave,j) dest = uniform base + lane*16 (HW req).
__device__ __forceinline__ void stage_lds_bf16(const unsigned short* __restrict__ src,
                                               int ld, int row0, int k0,
                                               unsigned short* __restrict__ dst,
                                               int tid) {
    #pragma unroll
    for (int j = 0; j < 2; ++j) {
        const int c = tid + j * 256;          // 512 chunks of 8 bf16 (16 B)
        const int r = c >> 2, kc = (c & 3) * 8;
        gload16(src + (size_t)(row0 + r) * ld + k0 + kc, dst + c * 8);
    }
}

// fp32 source: stage 128x32 with convert (register path; only PV's A needs it).
__device__ __forceinline__ void stage_cvt_f32(const float* __restrict__ src,
                                              int ld, int row0, int k0,
                                              unsigned short* __restrict__ dst,
                                              int tid) {
    #pragma unroll
    for (int i = 0; i < 4; ++i) {
        int c = tid + i * 256;                // 1024 chunks of 4 floats
        int r = c >> 3, kc = (c & 7) * 4;
        floatx4 v = *(const floatx4*)(src + (size_t)(row0 + r) * ld + k0 + kc);
        short4v p;
        p[0] = (short)f2bf(v[0]); p[1] = (short)f2bf(v[1]);
        p[2] = (short)f2bf(v[2]); p[3] = (short)f2bf(v[3]);
        *(short4v*)(dst + r * 32 + kc) = p;
    }
}

enum { M_PROJ_QK = 0, M_PROJ_V = 1, M_SCORES = 2, M_PV = 3, M_OUT = 4 };

// C = A @ B^T (+bias) (*scale). A:[M,K] ld=lda, B:[N,K] ld=ldb, row-major.
// 128x128 tile per 256-thread block, 4 waves each 64x64 via 4x4 mfma 16x16x32 bf16.
template<int MODE, typename TA, typename TB>
__launch_bounds__(256)
__global__ void gemm_abt(const TA* __restrict__ Ag, const TB* __restrict__ Bg,
                         const float* __restrict__ bias, void* __restrict__ Cg,
                         int K, int lda, int ldb, float scale) {
    const int m0 = blockIdx.y * 128;
    const int n0 = blockIdx.x * 128;
    int kEnd = K;
    const TA* Ap = Ag;
    const TB* Bp = Bg;

    if constexpr (MODE == M_SCORES) {
        if (n0 > m0 + 127) return;      // tile fully above causal diagonal
        const size_t z = blockIdx.z;
        Ap = Ag + z * (size_t)S_LEN * DKD;
        Bp = Bg + z * (size_t)S_LEN * DKD;
    }
    if constexpr (MODE == M_PV) {
        const size_t z = blockIdx.z;
        Ap = Ag + z * (size_t)S_LEN * S_LEN;
        Bp = Bg + z * (size_t)DKD * S_LEN;
        kEnd = m0 + 128;                // attn[m,k]==0 for k>m
    }

    __shared__ __align__(16) unsigned short As[128][32];
    __shared__ __align__(16) unsigned short Bs[128][32];

    const int tid  = threadIdx.x;
    const int lane = tid & 63;
    const int wave = tid >> 6;
    const int quad = lane >> 4;
    const int l16  = lane & 15;
    const int mw   = (wave >> 1) * 64;
    const int nw   = (wave & 1) * 64;

    floatx4 acc[4][4];
    #pragma unroll
    for (int i = 0; i < 4; ++i)
        #pragma unroll
        for (int j = 0; j < 4; ++j)
            acc[i][j] = (floatx4){0.f, 0.f, 0.f, 0.f};

    for (int k0 = 0; k0 < kEnd; k0 += 32) {
        if (k0 > 0) __syncthreads();
        // issue async bf16 gloads first; fp32 convert staging overlaps them
        if constexpr (sizeof(TB) == 2)
            stage_lds_bf16((const unsigned short*)Bp, ldb, n0, k0, &Bs[0][0], tid);
        if constexpr (sizeof(TA) == 2)
            stage_lds_bf16((const unsigned short*)Ap, lda, m0, k0, &As[0][0], tid);
        if constexpr (sizeof(TA) == 4)
            stage_cvt_f32((const float*)Ap, lda, m0, k0, &As[0][0], tid);
        if constexpr (sizeof(TB) == 4)
            stage_cvt_f32((const float*)Bp, ldb, n0, k0, &Bs[0][0], tid);
        __syncthreads();                // drains vmcnt (gload_lds) + lgkm

        short8 af[4], bf[4];
        #pragma unroll
        for (int i = 0; i < 4; ++i)
            af[i] = *(const short8*)&As[mw + i * 16 + l16][quad * 8];
        #pragma unroll
        for (int j = 0; j < 4; ++j)
            bf[j] = *(const short8*)&Bs[nw + j * 16 + l16][quad * 8];
        #pragma unroll
        for (int i = 0; i < 4; ++i)
            #pragma unroll
            for (int j = 0; j < 4; ++j)
                acc[i][j] = __builtin_amdgcn_mfma_f32_16x16x32_bf16(
                    af[i], bf[j], acc[i][j], 0, 0, 0);
    }

    // Epilogue: C/D layout col = lane&15, row = quad*4 + reg  [verified m89/m91]
    #pragma unroll
    for (int i = 0; i < 4; ++i) {
        #pragma unroll
        for (int j = 0; j < 4; ++j) {
            #pragma unroll
            for (int r = 0; r < 4; ++r) {
                const int row = m0 + mw + i * 16 + quad * 4 + r;
                const int col = n0 + nw + j * 16 + l16;
                float v = acc[i][j][r];
                if constexpr (MODE == M_PROJ_QK || MODE == M_PROJ_V) {
                    v += bias[col];
                    const int b = row >> 11, s = row & (S_LEN - 1);
                    const int h = col >> 7,  dk = col & (DKD - 1);
                    unsigned short* o = (unsigned short*)Cg;
                    if constexpr (MODE == M_PROJ_QK)
                        o[((size_t)(b * H_NUM + h) * S_LEN + s) * DKD + dk] = f2bf(v);
                    else
                        o[((size_t)(b * H_NUM + h) * DKD + dk) * S_LEN + s] = f2bf(v);
                } else if constexpr (MODE == M_SCORES) {
                    float* o = (float*)Cg + (size_t)blockIdx.z * S_LEN * S_LEN;
                    o[(size_t)row * S_LEN + col] = v * scale;
                } else if constexpr (MODE == M_PV) {
                    const int z = blockIdx.z, b = z >> 4, h = z & 15;
                    unsigned short* o = (unsigned short*)Cg;
                    o[((size_t)(b * S_LEN + row)) * D_DIM + h * DKD + col] = f2bf(v);
                } else {  // M_OUT
                    float* o = (float*)Cg;
                    o[(size_t)row * D_DIM + col] = v + bias[col];
                }
            }
        }
    }
}

// Causal softmax in place over attn [B*H, S, S]; one wave per row, float4 I/O.
// Masked cols (> row) written as exact 0.0 (ref: exp(-1e9 - max) underflows).
__launch_bounds__(256)
__global__ void softmax_causal(float* __restrict__ attn) {
    const int lane = threadIdx.x & 63;
    const int wave = threadIdx.x >> 6;
    const int s = blockIdx.x * 4 + wave;       // row
    float* rowp = attn + ((size_t)blockIdx.y * S_LEN + s) * S_LEN;

    floatx4 vals[8];
    float mx = -3.0e38f;
    #pragma unroll
    for (int j = 0; j < 8; ++j) {
        const int idx = lane * 4 + j * 256;
        floatx4 t = {-3.0e38f, -3.0e38f, -3.0e38f, -3.0e38f};
        if (idx <= s) t = *(const floatx4*)(rowp + idx);   // skip fully-masked loads
        #pragma unroll
        for (int e = 0; e < 4; ++e) {
            const float x = (idx + e <= s) ? t[e] : -3.0e38f;
            vals[j][e] = x;
            mx = fmaxf(mx, x);
        }
    }
    #pragma unroll
    for (int off = 32; off; off >>= 1) mx = fmaxf(mx, __shfl_down(mx, off, 64));
    mx = __shfl(mx, 0, 64);

    float sum = 0.f;
    #pragma unroll
    for (int j = 0; j < 8; ++j) {
        const int idx = lane * 4 + j * 256;
        #pragma unroll
        for (int e = 0; e < 4; ++e) {
            const float ev = (idx + e <= s) ? __expf(vals[j][e] - mx) : 0.f;
            vals[j][e] = ev;
            sum += ev;
        }
    }
    #pragma unroll
    for (int off = 32; off; off >>= 1) sum += __shfl_down(sum, off, 64);
    sum = __shfl(sum, 0, 64);

    const float inv = 1.f / sum;
    #pragma unroll
    for (int j = 0; j < 8; ++j) {
        const int idx = lane * 4 + j * 256;
        floatx4 o;
        #pragma unroll
        for (int e = 0; e < 4; ++e) o[e] = vals[j][e] * inv;
        *(floatx4*)(rowp + idx) = o;
    }
}

// fp32 -> bf16 bulk convert, 8 elems/thread.
__launch_bounds__(256)
__global__ void cvt_bf16(const float* __restrict__ src,
                         unsigned short* __restrict__ dst) {
    const size_t i = ((size_t)blockIdx.x * 256 + threadIdx.x) * 8;
    const floatx4 a = *(const floatx4*)(src + i);
    const floatx4 b = *(const floatx4*)(src + i + 4);
    short8 o;
    o[0] = (short)f2bf(a[0]); o[1] = (short)f2bf(a[1]);
    o[2] = (short)f2bf(a[2]); o[3] = (short)f2bf(a[3]);
    o[4] = (short)f2bf(b[0]); o[5] = (short)f2bf(b[1]);
    o[6] = (short)f2bf(b[2]); o[7] = (short)f2bf(b[3]);
    *(short8*)(dst + i) = o;
}

extern "C" void kernel_launch(void* const* d_in, const int* in_sizes, int n_in,
                              void* d_out, int out_size, void* d_ws, size_t ws_size,
                              hipStream_t stream) {
    const float* query = (const float*)d_in[0];
    const float* key_  = (const float*)d_in[1];
    const float* value = (const float*)d_in[2];
    const float* Wq = (const float*)d_in[3];
    const float* bq = (const float*)d_in[4];
    const float* Wk = (const float*)d_in[5];
    const float* bk = (const float*)d_in[6];
    const float* Wv = (const float*)d_in[7];
    const float* bv = (const float*)d_in[8];
    const float* Wo = (const float*)d_in[9];
    const float* bo = (const float*)d_in[10];

    float* out  = (float*)d_out;
    float* attn = out + (size_t)BATCH * S_LEN * D_DIM;

    const size_t NE = (size_t)BATCH * S_LEN * D_DIM;   // 8388608
    const size_t NW = (size_t)D_DIM * D_DIM;           // 4194304
    unsigned short* qb = (unsigned short*)d_ws;
    unsigned short* kb = qb + NE;
    unsigned short* vT = kb + NE;
    unsigned short* xb = vT + NE;
    unsigned short* qf = xb + NE;
    unsigned short* kf = qf + NE;
    unsigned short* vf = kf + NE;
    unsigned short* wq = vf + NE;
    unsigned short* wk = wq + NW;
    unsigned short* wv = wk + NW;
    unsigned short* wo = wv + NW;

    const dim3 blk(256);
    const float iscale = 0.088388347648318447f;        // 1/sqrt(128)

    // One-time fp32 -> bf16 conversion of inputs + weights
    cvt_bf16<<<dim3(NE / 2048), blk, 0, stream>>>(query, qf);
    cvt_bf16<<<dim3(NE / 2048), blk, 0, stream>>>(key_,  kf);
    cvt_bf16<<<dim3(NE / 2048), blk, 0, stream>>>(value, vf);
    cvt_bf16<<<dim3(NW / 2048), blk, 0, stream>>>(Wq, wq);
    cvt_bf16<<<dim3(NW / 2048), blk, 0, stream>>>(Wk, wk);
    cvt_bf16<<<dim3(NW / 2048), blk, 0, stream>>>(Wv, wv);
    cvt_bf16<<<dim3(NW / 2048), blk, 0, stream>>>(Wo, wo);

    // QKV projections: [4096,2048] @ [2048,2048]^T, all-bf16 global_load_lds path
    const dim3 gproj(D_DIM / 128, (BATCH * S_LEN) / 128, 1);
    gemm_abt<M_PROJ_QK, unsigned short, unsigned short><<<gproj, blk, 0, stream>>>(
        qf, wq, bq, qb, D_DIM, D_DIM, D_DIM, 1.f);
    gemm_abt<M_PROJ_QK, unsigned short, unsigned short><<<gproj, blk, 0, stream>>>(
        kf, wk, bk, kb, D_DIM, D_DIM, D_DIM, 1.f);
    gemm_abt<M_PROJ_V, unsigned short, unsigned short><<<gproj, blk, 0, stream>>>(
        vf, wv, bv, vT, D_DIM, D_DIM, D_DIM, 1.f);

    // Scores: per (b,h)  q[S,DK] @ k[S,DK]^T * 1/sqrt(DK), causal tiles only
    const dim3 gsc(S_LEN / 128, S_LEN / 128, BATCH * H_NUM);
    gemm_abt<M_SCORES, unsigned short, unsigned short><<<gsc, blk, 0, stream>>>(
        qb, kb, nullptr, attn, DKD, DKD, DKD, iscale);

    // Causal softmax in place
    softmax_causal<<<dim3(S_LEN / 4, BATCH * H_NUM), blk, 0, stream>>>(attn);

    // PV: per (b,h)  attn[S,S] @ vT[DK,S]^T, K limited to m0+128
    const dim3 gpv(1, S_LEN / 128, BATCH * H_NUM);
    gemm_abt<M_PV, float, unsigned short><<<gpv, blk, 0, stream>>>(
        attn, vT, nullptr, xb, S_LEN, S_LEN, S_LEN, 1.f);

    // Output projection: x[4096,2048] @ Wo^T + bo -> fp32 out
    const dim3 gout(D_DIM / 128, (BATCH * S_LEN) / 128, 1);
    gemm_abt<M_OUT, unsigned short, unsigned short><<<gout, blk, 0, stream>>>(
        xb, wo, bo, out, D_DIM, D_DIM, D_DIM, 1.f);
}